// Round 3
// baseline (1192.409 us; speedup 1.0000x reference)
//
#include <hip/hip_runtime.h>

#define N_NODES 100000
#define N_EDGES 1600000
#define NFEAT 128
#define NHID 64
#define NOUT 32

#define NPB 128                                  // nodes per bucket (dst >> 7)
#define NB ((N_NODES + NPB - 1) / NPB)           // 782 buckets
#define CHUNK 4096                               // edges per scatter/hist block
#define NCHUNK ((N_EDGES + CHUNK - 1) / CHUNK)   // 391

// ---------------------------------------------------------------
// GEMM1: support[N,64] = x[N,128] @ W1[128,64]
// ---------------------------------------------------------------
__global__ __launch_bounds__(256) void gemm1_kernel(const float* __restrict__ x,
                                                    const float* __restrict__ W1,
                                                    float* __restrict__ support) {
    __shared__ float wlds[NFEAT * NHID];   // 32 KB
    __shared__ float xs[4][NFEAT];
    const int tid = threadIdx.x;
    for (int i = tid; i < NFEAT * NHID; i += 256) wlds[i] = W1[i];

    const int col = tid & 63;
    const int nl  = tid >> 6;
    const int base = blockIdx.x * 64;

    for (int it = 0; it < 64; it += 4) {
        const int n0 = base + it;
        __syncthreads();
        {
            const int r  = tid >> 7, c = tid & 127;
            const int n  = n0 + r;
            xs[r][c] = (n < N_NODES) ? x[(size_t)n * NFEAT + c] : 0.f;
            const int r2 = (tid + 256) >> 7;
            const int n2 = n0 + r2;
            xs[r2][c] = (n2 < N_NODES) ? x[(size_t)n2 * NFEAT + c] : 0.f;
        }
        __syncthreads();
        const int n = n0 + nl;
        if (n < N_NODES) {
            float acc = 0.f;
#pragma unroll
            for (int k = 0; k < NFEAT; ++k)
                acc += xs[nl][k] * wlds[k * NHID + col];
            support[(size_t)n * NHID + col] = acc;
        }
    }
}

// ---------------------------------------------------------------
// bucket CSR build: zero -> hist (LDS-aggregated) -> scan -> scatter
// ---------------------------------------------------------------
__global__ __launch_bounds__(256) void zero_counts_kernel(int* __restrict__ counts) {
    int i = blockIdx.x * 256 + threadIdx.x;
    if (i < NB) counts[i] = 0;
}

__global__ __launch_bounds__(256) void bucket_hist_kernel(const int* __restrict__ dst,
                                                          int* __restrict__ counts) {
    __shared__ int cnt[NB];
    const int tid = threadIdx.x;
    for (int i = tid; i < NB; i += 256) cnt[i] = 0;
    __syncthreads();
    const int cbase = blockIdx.x * CHUNK;
    for (int k = 0; k < CHUNK; k += 256) {
        int e = cbase + k + tid;
        if (e < N_EDGES) atomicAdd(&cnt[dst[e] >> 7], 1);
    }
    __syncthreads();
    for (int i = tid; i < NB; i += 256) {
        int c = cnt[i];
        if (c) atomicAdd(&counts[i], c);
    }
}

// single block: exclusive scan of NB counts -> base[NB+1], cursor copy
__global__ __launch_bounds__(256) void bucket_scan_kernel(const int* __restrict__ counts,
                                                          int* __restrict__ base,
                                                          int* __restrict__ cursor) {
    __shared__ int lds[256];
    const int tid = threadIdx.x;
    int v[4]; int tsum = 0;
#pragma unroll
    for (int i = 0; i < 4; ++i) {
        int idx = tid * 4 + i;
        v[i] = (idx < NB) ? counts[idx] : 0;
        tsum += v[i];
    }
    lds[tid] = tsum;
    __syncthreads();
    int val = tsum;
    for (int off = 1; off < 256; off <<= 1) {
        int add = (tid >= off) ? lds[tid - off] : 0;
        __syncthreads();
        val += add;
        lds[tid] = val;
        __syncthreads();
    }
    int excl = val - tsum;
#pragma unroll
    for (int i = 0; i < 4; ++i) {
        int idx = tid * 4 + i;
        if (idx < NB) { base[idx] = excl; cursor[idx] = excl; excl += v[i]; }
    }
    if (tid == 255) base[NB] = N_EDGES;
}

// LDS-staged grouped scatter: per 4096-edge chunk, group records by bucket in
// LDS, reserve per-bucket global ranges (1 atomic/bucket), write coalesced runs.
// record: x = src(17b) | dstLocal(7b)<<17 ; y = val bits
__global__ __launch_bounds__(256) void bucket_scatter_kernel(const float* __restrict__ vals,
                                                             const int* __restrict__ src,
                                                             const int* __restrict__ dst,
                                                             int* __restrict__ cursor,
                                                             uint2* __restrict__ recs) {
    __shared__ int cnt[NB];
    __shared__ int sbase[NB];
    __shared__ int cur[NB];
    __shared__ int gbase[NB];
    __shared__ uint2 rl[CHUNK];                 // 32 KB
    __shared__ unsigned short slotB[CHUNK];     // 8 KB
    __shared__ int scan_lds[256];
    const int tid = threadIdx.x;
    const int cbase = blockIdx.x * CHUNK;
    const int m = min(CHUNK, N_EDGES - cbase);

    for (int i = tid; i < NB; i += 256) cnt[i] = 0;
    int dstv[CHUNK / 256];
    __syncthreads();
#pragma unroll
    for (int k = 0; k < CHUNK / 256; ++k) {
        int e = cbase + k * 256 + tid;
        int d = (e < N_EDGES) ? dst[e] : -1;
        dstv[k] = d;
        if (d >= 0) atomicAdd(&cnt[d >> 7], 1);
    }
    __syncthreads();
    {   // exclusive scan cnt -> sbase, init cur
        int v[4]; int tsum = 0;
#pragma unroll
        for (int i = 0; i < 4; ++i) {
            int idx = tid * 4 + i;
            v[i] = (idx < NB) ? cnt[idx] : 0;
            tsum += v[i];
        }
        scan_lds[tid] = tsum;
        __syncthreads();
        int val = tsum;
        for (int off = 1; off < 256; off <<= 1) {
            int add = (tid >= off) ? scan_lds[tid - off] : 0;
            __syncthreads();
            val += add;
            scan_lds[tid] = val;
            __syncthreads();
        }
        int excl = val - tsum;
#pragma unroll
        for (int i = 0; i < 4; ++i) {
            int idx = tid * 4 + i;
            if (idx < NB) { sbase[idx] = excl; cur[idx] = excl; excl += v[i]; }
        }
    }
    __syncthreads();
    // reserve global ranges (one atomic per non-empty bucket)
    for (int b = tid; b < NB; b += 256) {
        int c = cnt[b];
        gbase[b] = c ? atomicAdd(&cursor[b], c) : 0;
    }
    // place records into LDS, grouped by bucket
#pragma unroll
    for (int k = 0; k < CHUNK / 256; ++k) {
        int e = cbase + k * 256 + tid;
        int d = dstv[k];
        if (d >= 0) {
            int b = d >> 7;
            int slot = atomicAdd(&cur[b], 1);
            rl[slot] = make_uint2((unsigned)src[e] | ((unsigned)(d & (NPB - 1)) << 17),
                                  __float_as_uint(vals[e]));
            slotB[slot] = (unsigned short)b;
        }
    }
    __syncthreads();
    // coalesced writeout: consecutive slots within a bucket -> consecutive global
    for (int i = tid; i < m; i += 256) {
        int b = slotB[i];
        recs[gbase[b] + (i - sbase[b])] = rl[i];
    }
}

// ---------------------------------------------------------------
// SpMM1 (bucketed): LDS acc[128 nodes][64], lane = feature,
// one wave per edge, LDS float atomics (2-way bank alias = free).
// epilogue: h = relu(acc + b1), one plain store per element.
// ---------------------------------------------------------------
__global__ __launch_bounds__(256) void spmm1_bucket_kernel(const int* __restrict__ base,
                                                           const uint2* __restrict__ recs,
                                                           const float* __restrict__ dense,
                                                           const float* __restrict__ b1,
                                                           float* __restrict__ h) {
    __shared__ float acc[NPB * NHID];   // 32 KB
    const int tid = threadIdx.x;
    const int lane = tid & 63, wid = tid >> 6;
    for (int i = tid; i < NPB * NHID; i += 256) acc[i] = 0.f;
    __syncthreads();
    const int b = blockIdx.x;
    const int bb = base[b], be = base[b + 1];
#pragma unroll 4
    for (int e = bb + wid; e < be; e += 4) {
        uint2 r = recs[e];
        int   s  = r.x & 0x1FFFF;
        int   dl = (r.x >> 17) & (NPB - 1);
        float v  = __uint_as_float(r.y);
        atomicAdd(&acc[dl * NHID + lane], v * dense[(size_t)s * NHID + lane]);
    }
    __syncthreads();
    const int node0 = b * NPB;
    for (int i = tid; i < NPB * NHID; i += 256) {
        int node = node0 + (i >> 6);
        if (node < N_NODES)
            h[(size_t)node * NHID + (i & 63)] = fmaxf(acc[i] + b1[i & 63], 0.f);
    }
}

// ---------------------------------------------------------------
// GEMM2: s2[N,32] = h[N,64] @ W2[64,32]
// ---------------------------------------------------------------
__global__ __launch_bounds__(256) void gemm2_kernel(const float* __restrict__ h,
                                                    const float* __restrict__ W2,
                                                    float* __restrict__ s2) {
    __shared__ float wlds[NHID * NOUT];
    __shared__ float xs[8][NHID];
    const int tid = threadIdx.x;
    for (int i = tid; i < NHID * NOUT; i += 256) wlds[i] = W2[i];

    const int col = tid & 31;
    const int nl  = tid >> 5;
    const int base = blockIdx.x * 128;

    for (int it = 0; it < 128; it += 8) {
        const int n0 = base + it;
        __syncthreads();
        {
            const int r  = tid >> 6, c = tid & 63;
            const int n  = n0 + r;
            xs[r][c] = (n < N_NODES) ? h[(size_t)n * NHID + c] : 0.f;
            const int r2 = (tid + 256) >> 6;
            const int n2 = n0 + r2;
            xs[r2][c] = (n2 < N_NODES) ? h[(size_t)n2 * NHID + c] : 0.f;
        }
        __syncthreads();
        const int n = n0 + nl;
        if (n < N_NODES) {
            float acc = 0.f;
#pragma unroll
            for (int k = 0; k < NHID; ++k)
                acc += xs[nl][k] * wlds[k * NOUT + col];
            s2[(size_t)n * NOUT + col] = acc;
        }
    }
}

// ---------------------------------------------------------------
// SpMM2 (bucketed): LDS acc[128 nodes][32], half-wave per edge.
// epilogue: out = acc + b2.
// ---------------------------------------------------------------
__global__ __launch_bounds__(256) void spmm2_bucket_kernel(const int* __restrict__ base,
                                                           const uint2* __restrict__ recs,
                                                           const float* __restrict__ dense,
                                                           const float* __restrict__ b2,
                                                           float* __restrict__ out) {
    __shared__ float acc[NPB * NOUT];   // 16 KB
    const int tid = threadIdx.x;
    const int l32 = tid & 31;
    const int sub = (tid >> 5) & 1;
    const int wid = tid >> 6;
    for (int i = tid; i < NPB * NOUT; i += 256) acc[i] = 0.f;
    __syncthreads();
    const int b = blockIdx.x;
    const int bb = base[b], be = base[b + 1];
#pragma unroll 4
    for (int e = bb + wid * 2 + sub; e < be; e += 8) {
        uint2 r = recs[e];
        int   s  = r.x & 0x1FFFF;
        int   dl = (r.x >> 17) & (NPB - 1);
        float v  = __uint_as_float(r.y);
        atomicAdd(&acc[dl * NOUT + l32], v * dense[(size_t)s * NOUT + l32]);
    }
    __syncthreads();
    const int node0 = b * NPB;
    for (int i = tid; i < NPB * NOUT; i += 256) {
        int node = node0 + (i >> 5);
        if (node < N_NODES)
            out[(size_t)node * NOUT + (i & 31)] = acc[i] + b2[i & 31];
    }
}

extern "C" void kernel_launch(void* const* d_in, const int* in_sizes, int n_in,
                              void* d_out, int out_size, void* d_ws, size_t ws_size,
                              hipStream_t stream) {
    const float* x        = (const float*)d_in[0];
    const float* adj_vals = (const float*)d_in[1];
    const float* W1       = (const float*)d_in[2];
    const float* b1       = (const float*)d_in[3];
    const float* W2       = (const float*)d_in[4];
    const float* b2       = (const float*)d_in[5];
    const int*   esrc     = (const int*)d_in[6];
    const int*   edst     = (const int*)d_in[7];
    float*       out      = (float*)d_out;

    // workspace layout (all fully rewritten every call):
    float* support = (float*)d_ws;                        // 6.4M f (s2 reuses)
    float* h       = support + (size_t)N_NODES * NHID;    // 6.4M f
    uint2* recs    = (uint2*)(h + (size_t)N_NODES * NHID);// 1.6M uint2
    int*   counts  = (int*)(recs + N_EDGES);              // NB
    int*   base    = counts + 1024;                       // NB+1
    int*   cursor  = base + 1024;                         // NB

    // 1. support = x @ W1
    gemm1_kernel<<<(N_NODES + 63) / 64, 256, 0, stream>>>(x, W1, support);

    // 2. bucket build (shared by both SpMMs)
    zero_counts_kernel<<<(NB + 255) / 256, 256, 0, stream>>>(counts);
    bucket_hist_kernel<<<NCHUNK, 256, 0, stream>>>(edst, counts);
    bucket_scan_kernel<<<1, 256, 0, stream>>>(counts, base, cursor);
    bucket_scatter_kernel<<<NCHUNK, 256, 0, stream>>>(adj_vals, esrc, edst, cursor, recs);

    // 3. h = relu(A @ support + b1)
    spmm1_bucket_kernel<<<NB, 256, 0, stream>>>(base, recs, support, b1, h);

    // 4. s2 = h @ W2  (into support region)
    gemm2_kernel<<<(N_NODES + 127) / 128, 256, 0, stream>>>(h, W2, support);

    // 5. out = A @ s2 + b2
    spmm2_bucket_kernel<<<NB, 256, 0, stream>>>(base, recs, support, b2, out);
}

// Round 4
// 270.211 us; speedup vs baseline: 4.4129x; 4.4129x over previous
//
#include <hip/hip_runtime.h>

#define N_NODES 100000
#define N_EDGES 1600000
#define NFEAT 128
#define NHID 64
#define NOUT 32

#define NPB 256                                  // nodes per bucket (dst >> 8)
#define NB ((N_NODES + NPB - 1) / NPB)           // 391 buckets
#define CHUNK 4096                               // edges per scatter/hist block
#define NCHUNK ((N_EDGES + CHUNK - 1) / CHUNK)   // 391

// ---------------------------------------------------------------
// GEMM1: support[N,64] = x[N,128] @ W1[128,64]
// lane owns 4 adjacent cols: 1 ds_read_b128 (W) + 1 broadcast (x) per k.
// ---------------------------------------------------------------
__global__ __launch_bounds__(256) void gemm1_kernel(const float* __restrict__ x,
                                                    const float* __restrict__ W1,
                                                    float* __restrict__ support) {
    __shared__ float wlds[NFEAT * NHID];      // 32 KB, [k][col]
    __shared__ float xs[16][NFEAT + 1];       // padded rows -> conflict-free
    const int tid = threadIdx.x;
    for (int i = tid; i < NFEAT * NHID; i += 256) wlds[i] = W1[i];

    const int cg = (tid & 15) * 4;            // col group (0,4,..,60)
    const int nl = tid >> 4;                  // node-in-tile 0..15
    const int base = blockIdx.x * 64;

    for (int it = 0; it < 64; it += 16) {
        const int n0 = base + it;
        __syncthreads();
        {   // stage 16 rows x 128: each thread 8 consecutive floats
            const int r = tid >> 4, c = (tid & 15) * 8;
            const int n = n0 + r;
            if (n < N_NODES) {
                const float4* p = (const float4*)&x[(size_t)n * NFEAT + c];
                *(float4*)&xs[r][c]     = p[0];
                *(float4*)&xs[r][c + 4] = p[1];
            } else {
                *(float4*)&xs[r][c]     = make_float4(0, 0, 0, 0);
                *(float4*)&xs[r][c + 4] = make_float4(0, 0, 0, 0);
            }
        }
        __syncthreads();
        float a0 = 0.f, a1 = 0.f, a2 = 0.f, a3 = 0.f;
#pragma unroll
        for (int k = 0; k < NFEAT; ++k) {
            float4 w = *(const float4*)&wlds[k * NHID + cg];
            float xv = xs[nl][k];
            a0 += w.x * xv; a1 += w.y * xv; a2 += w.z * xv; a3 += w.w * xv;
        }
        const int n = n0 + nl;
        if (n < N_NODES)
            *(float4*)&support[(size_t)n * NHID + cg] = make_float4(a0, a1, a2, a3);
    }
}

// ---------------------------------------------------------------
// bucket build: zero -> hist(LDS) -> scan -> coarse scatter -> fine sort
// ---------------------------------------------------------------
__global__ __launch_bounds__(256) void zero_counts_kernel(int* __restrict__ counts) {
    int i = blockIdx.x * 256 + threadIdx.x;
    if (i < NB) counts[i] = 0;
}

__global__ __launch_bounds__(256) void bucket_hist_kernel(const int* __restrict__ dst,
                                                          int* __restrict__ counts) {
    __shared__ int cnt[NB];
    const int tid = threadIdx.x;
    for (int i = tid; i < NB; i += 256) cnt[i] = 0;
    __syncthreads();
    const int cbase = blockIdx.x * CHUNK;
#pragma unroll
    for (int k = 0; k < CHUNK; k += 256) {
        int e = cbase + k + tid;
        if (e < N_EDGES) atomicAdd(&cnt[dst[e] >> 8], 1);
    }
    __syncthreads();
    for (int i = tid; i < NB; i += 256) {
        int c = cnt[i];
        if (c) atomicAdd(&counts[i], c);
    }
}

// single block: exclusive scan of NB counts -> cbase[NB+1], cursor copy
__global__ __launch_bounds__(256) void bucket_scan_kernel(const int* __restrict__ counts,
                                                          int* __restrict__ cbase,
                                                          int* __restrict__ cursor) {
    __shared__ int lds[256];
    const int tid = threadIdx.x;
    int v[4]; int tsum = 0;
#pragma unroll
    for (int i = 0; i < 4; ++i) {
        int idx = tid * 4 + i;
        v[i] = (idx < NB) ? counts[idx] : 0;
        tsum += v[i];
    }
    lds[tid] = tsum;
    __syncthreads();
    int val = tsum;
    for (int off = 1; off < 256; off <<= 1) {
        int add = (tid >= off) ? lds[tid - off] : 0;
        __syncthreads();
        val += add;
        lds[tid] = val;
        __syncthreads();
    }
    int excl = val - tsum;
#pragma unroll
    for (int i = 0; i < 4; ++i) {
        int idx = tid * 4 + i;
        if (idx < NB) { cbase[idx] = excl; cursor[idx] = excl; excl += v[i]; }
    }
    if (tid == 255) cbase[NB] = N_EDGES;
}

// coarse scatter: group chunk records by bucket in LDS, reserve per-bucket
// global ranges (1 atomic/bucket), write coalesced runs.
// record: x = src(17b) | dstLocal(8b)<<17 ; y = val bits
__global__ __launch_bounds__(256) void bucket_scatter_kernel(const float* __restrict__ vals,
                                                             const int* __restrict__ src,
                                                             const int* __restrict__ dst,
                                                             int* __restrict__ cursor,
                                                             uint2* __restrict__ recs) {
    __shared__ int cnt[NB];
    __shared__ int sbase[NB];
    __shared__ int cur[NB];
    __shared__ int gbase[NB];
    __shared__ uint2 rl[CHUNK];                 // 32 KB
    __shared__ unsigned short slotB[CHUNK];     // 8 KB
    __shared__ int scan_lds[256];
    const int tid = threadIdx.x;
    const int cbase0 = blockIdx.x * CHUNK;
    const int m = min(CHUNK, N_EDGES - cbase0);

    for (int i = tid; i < NB; i += 256) cnt[i] = 0;
    int dstv[CHUNK / 256];
    __syncthreads();
#pragma unroll
    for (int k = 0; k < CHUNK / 256; ++k) {
        int e = cbase0 + k * 256 + tid;
        int d = (e < N_EDGES) ? dst[e] : -1;
        dstv[k] = d;
        if (d >= 0) atomicAdd(&cnt[d >> 8], 1);
    }
    __syncthreads();
    {   // exclusive scan cnt -> sbase, init cur
        int v[4]; int tsum = 0;
#pragma unroll
        for (int i = 0; i < 4; ++i) {
            int idx = tid * 4 + i;
            v[i] = (idx < NB) ? cnt[idx] : 0;
            tsum += v[i];
        }
        scan_lds[tid] = tsum;
        __syncthreads();
        int val = tsum;
        for (int off = 1; off < 256; off <<= 1) {
            int add = (tid >= off) ? scan_lds[tid - off] : 0;
            __syncthreads();
            val += add;
            scan_lds[tid] = val;
            __syncthreads();
        }
        int excl = val - tsum;
#pragma unroll
        for (int i = 0; i < 4; ++i) {
            int idx = tid * 4 + i;
            if (idx < NB) { sbase[idx] = excl; cur[idx] = excl; excl += v[i]; }
        }
    }
    __syncthreads();
    for (int b = tid; b < NB; b += 256) {
        int c = cnt[b];
        gbase[b] = c ? atomicAdd(&cursor[b], c) : 0;
    }
#pragma unroll
    for (int k = 0; k < CHUNK / 256; ++k) {
        int e = cbase0 + k * 256 + tid;
        int d = dstv[k];
        if (d >= 0) {
            int b = d >> 8;
            int slot = atomicAdd(&cur[b], 1);
            rl[slot] = make_uint2((unsigned)src[e] | ((unsigned)(d & (NPB - 1)) << 17),
                                  __float_as_uint(vals[e]));
            slotB[slot] = (unsigned short)b;
        }
    }
    __syncthreads();
    for (int i = tid; i < m; i += 256) {
        int b = slotB[i];
        recs[gbase[b] + (i - sbase[b])] = rl[i];
    }
}

// fine sort: one block per bucket; counting-sort its records into exact
// per-node order (writes land in a 32KB L2-resident window) + emit offs.
__global__ __launch_bounds__(256) void fine_sort_kernel(const int* __restrict__ cbase,
                                                        const uint2* __restrict__ recsC,
                                                        uint2* __restrict__ recs2,
                                                        int* __restrict__ offs) {
    __shared__ int cnt[NPB];
    __shared__ int cur[NPB];
    __shared__ int scan_lds[256];
    const int tid = threadIdx.x;
    const int b = blockIdx.x;
    const int s = cbase[b], e = cbase[b + 1];
    cnt[tid] = 0;
    __syncthreads();
    for (int i = s + tid; i < e; i += 256)
        atomicAdd(&cnt[(recsC[i].x >> 17) & (NPB - 1)], 1);
    __syncthreads();
    int v = cnt[tid];
    scan_lds[tid] = v;
    __syncthreads();
    int val = v;
    for (int off = 1; off < 256; off <<= 1) {
        int add = (tid >= off) ? scan_lds[tid - off] : 0;
        __syncthreads();
        val += add;
        scan_lds[tid] = val;
        __syncthreads();
    }
    int excl = val - v;
    cur[tid] = excl;
    const int node = b * NPB + tid;
    if (node < N_NODES) offs[node] = s + excl;
    if (b == 0 && tid == 0) offs[N_NODES] = N_EDGES;
    __syncthreads();
    for (int i = s + tid; i < e; i += 256) {
        uint2 r = recsC[i];
        int dl = (r.x >> 17) & (NPB - 1);
        int p = atomicAdd(&cur[dl], 1);
        recs2[s + p] = make_uint2(r.x & 0x1FFFF, r.y);
    }
}

// ---------------------------------------------------------------
// SpMM1 (CSR): h[d,:] = relu( sum val*support[src,:] + b1 )
// one wave per node, lane = feature, unroll 4.
// ---------------------------------------------------------------
__global__ __launch_bounds__(256) void spmm1_csr_kernel(const int* __restrict__ offs,
                                                        const uint2* __restrict__ recs,
                                                        const float* __restrict__ dense,
                                                        const float* __restrict__ b1,
                                                        float* __restrict__ h) {
    const int lane = threadIdx.x & 63;
    const int d = (blockIdx.x * 256 + threadIdx.x) >> 6;
    if (d >= N_NODES) return;
    const int start = offs[d], end = offs[d + 1];
    float a0 = 0.f, a1 = 0.f, a2 = 0.f, a3 = 0.f;
    int e = start;
    for (; e + 3 < end; e += 4) {
        uint2 r0 = recs[e], r1 = recs[e + 1], r2 = recs[e + 2], r3 = recs[e + 3];
        a0 += __uint_as_float(r0.y) * dense[(size_t)r0.x * NHID + lane];
        a1 += __uint_as_float(r1.y) * dense[(size_t)r1.x * NHID + lane];
        a2 += __uint_as_float(r2.y) * dense[(size_t)r2.x * NHID + lane];
        a3 += __uint_as_float(r3.y) * dense[(size_t)r3.x * NHID + lane];
    }
    for (; e < end; ++e) {
        uint2 r = recs[e];
        a0 += __uint_as_float(r.y) * dense[(size_t)r.x * NHID + lane];
    }
    h[(size_t)d * NHID + lane] = fmaxf((a0 + a1) + (a2 + a3) + b1[lane], 0.f);
}

// ---------------------------------------------------------------
// GEMM2: s2[N,32] = h[N,64] @ W2[64,32]
// ---------------------------------------------------------------
__global__ __launch_bounds__(256) void gemm2_kernel(const float* __restrict__ h,
                                                    const float* __restrict__ W2,
                                                    float* __restrict__ s2) {
    __shared__ float wlds[NHID * NOUT];       // 8 KB
    __shared__ float xs[32][NHID + 1];
    const int tid = threadIdx.x;
    for (int i = tid; i < NHID * NOUT; i += 256) wlds[i] = W2[i];

    const int cg = (tid & 7) * 4;
    const int nl = tid >> 3;                  // 0..31
    const int base = blockIdx.x * 128;

    for (int it = 0; it < 128; it += 32) {
        const int n0 = base + it;
        __syncthreads();
        {   // stage 32 rows x 64: each thread 8 consecutive floats
            const int r = tid >> 3, c = (tid & 7) * 8;
            const int n = n0 + r;
            if (n < N_NODES) {
                const float4* p = (const float4*)&h[(size_t)n * NHID + c];
                *(float4*)&xs[r][c]     = p[0];
                *(float4*)&xs[r][c + 4] = p[1];
            } else {
                *(float4*)&xs[r][c]     = make_float4(0, 0, 0, 0);
                *(float4*)&xs[r][c + 4] = make_float4(0, 0, 0, 0);
            }
        }
        __syncthreads();
        float a0 = 0.f, a1 = 0.f, a2 = 0.f, a3 = 0.f;
#pragma unroll
        for (int k = 0; k < NHID; ++k) {
            float4 w = *(const float4*)&wlds[k * NOUT + cg];
            float xv = xs[nl][k];
            a0 += w.x * xv; a1 += w.y * xv; a2 += w.z * xv; a3 += w.w * xv;
        }
        const int n = n0 + nl;
        if (n < N_NODES)
            *(float4*)&s2[(size_t)n * NOUT + cg] = make_float4(a0, a1, a2, a3);
    }
}

// ---------------------------------------------------------------
// SpMM2 (CSR): out[d,:] = sum val*s2[src,:] + b2
// one wave per node; 32-lane halves split edges by parity.
// ---------------------------------------------------------------
__global__ __launch_bounds__(256) void spmm2_csr_kernel(const int* __restrict__ offs,
                                                        const uint2* __restrict__ recs,
                                                        const float* __restrict__ dense,
                                                        const float* __restrict__ b2,
                                                        float* __restrict__ out) {
    const int lane = threadIdx.x & 63;
    const int half = lane >> 5, l32 = lane & 31;
    const int d = (blockIdx.x * 256 + threadIdx.x) >> 6;
    if (d >= N_NODES) return;
    const int start = offs[d], end = offs[d + 1];
    float a0 = 0.f, a1 = 0.f;
    int e = start + half;
    for (; e + 2 < end; e += 4) {
        uint2 r0 = recs[e], r1 = recs[e + 2];
        a0 += __uint_as_float(r0.y) * dense[(size_t)r0.x * NOUT + l32];
        a1 += __uint_as_float(r1.y) * dense[(size_t)r1.x * NOUT + l32];
    }
    if (e < end) {
        uint2 r = recs[e];
        a0 += __uint_as_float(r.y) * dense[(size_t)r.x * NOUT + l32];
    }
    float acc = a0 + a1;
    acc += __shfl_xor(acc, 32, 64);
    if (half == 0) out[(size_t)d * NOUT + l32] = acc + b2[l32];
}

extern "C" void kernel_launch(void* const* d_in, const int* in_sizes, int n_in,
                              void* d_out, int out_size, void* d_ws, size_t ws_size,
                              hipStream_t stream) {
    const float* x        = (const float*)d_in[0];
    const float* adj_vals = (const float*)d_in[1];
    const float* W1       = (const float*)d_in[2];
    const float* b1       = (const float*)d_in[3];
    const float* W2       = (const float*)d_in[4];
    const float* b2       = (const float*)d_in[5];
    const int*   esrc     = (const int*)d_in[6];
    const int*   edst     = (const int*)d_in[7];
    float*       out      = (float*)d_out;

    // ws layout (~64.5 MB, all rewritten every call):
    //   support[6.4M f] | h[6.4M f] (coarse recs alias h; dead before h write)
    //   | recs2[1.6M uint2] | offs[N+1] | counts | cbase | cursor
    float* support = (float*)d_ws;
    float* h       = support + (size_t)N_NODES * NHID;
    uint2* recsC   = (uint2*)h;                              // alias: coarse recs
    uint2* recs2   = (uint2*)(h + (size_t)N_NODES * NHID);
    int*   offs    = (int*)(recs2 + N_EDGES);                // N+1
    int*   counts  = offs + (N_NODES + 2);
    int*   cbase   = counts + 512;                           // NB+1
    int*   cursor  = cbase + 512;                            // NB

    // 1. support = x @ W1
    gemm1_kernel<<<(N_NODES + 63) / 64, 256, 0, stream>>>(x, W1, support);

    // 2. bucket CSR build (shared by both SpMMs)
    zero_counts_kernel<<<(NB + 255) / 256, 256, 0, stream>>>(counts);
    bucket_hist_kernel<<<NCHUNK, 256, 0, stream>>>(edst, counts);
    bucket_scan_kernel<<<1, 256, 0, stream>>>(counts, cbase, cursor);
    bucket_scatter_kernel<<<NCHUNK, 256, 0, stream>>>(adj_vals, esrc, edst, cursor, recsC);
    fine_sort_kernel<<<NB, 256, 0, stream>>>(cbase, recsC, recs2, offs);

    // 3. h = relu(A @ support + b1)   (overwrites recsC region — recsC is dead)
    spmm1_csr_kernel<<<(N_NODES * 64 + 255) / 256, 256, 0, stream>>>(offs, recs2,
                                                                     support, b1, h);

    // 4. s2 = h @ W2  (into support region)
    gemm2_kernel<<<(N_NODES + 127) / 128, 256, 0, stream>>>(h, W2, support);

    // 5. out = A @ s2 + b2
    spmm2_csr_kernel<<<(N_NODES * 64 + 255) / 256, 256, 0, stream>>>(offs, recs2,
                                                                     support, b2, out);
}

// Round 5
// 259.682 us; speedup vs baseline: 4.5918x; 1.0405x over previous
//
#include <hip/hip_runtime.h>
#include <hip/hip_fp16.h>

#define N_NODES 100000
#define N_EDGES 1600000
#define NFEAT 128
#define NHID 64
#define NOUT 32

#define NPB 256                                  // nodes per bucket (dst >> 8)
#define NB ((N_NODES + NPB - 1) / NPB)           // 391 buckets
#define CHUNK 4096                               // edges per scatter/hist block
#define NCHUNK ((N_EDGES + CHUNK - 1) / CHUNK)   // 391

// ---------------------------------------------------------------
// GEMM1: support[N,64] (fp16) = x[N,128] @ W1[128,64]
// lane owns 4 adjacent cols: 1 ds_read_b128 (W) + 1 broadcast (x) per k.
// ---------------------------------------------------------------
__global__ __launch_bounds__(256) void gemm1_kernel(const float* __restrict__ x,
                                                    const float* __restrict__ W1,
                                                    __half* __restrict__ support) {
    __shared__ float wlds[NFEAT * NHID];      // 32 KB, [k][col]
    __shared__ float xs[16][NFEAT + 1];
    const int tid = threadIdx.x;
    for (int i = tid; i < NFEAT * NHID; i += 256) wlds[i] = W1[i];

    const int cg = (tid & 15) * 4;            // col group (0,4,..,60)
    const int nl = tid >> 4;                  // node-in-tile 0..15
    const int base = blockIdx.x * 64;

    for (int it = 0; it < 64; it += 16) {
        const int n0 = base + it;
        __syncthreads();
        {
            const int r = tid >> 4, c = (tid & 15) * 8;
            const int n = n0 + r;
            if (n < N_NODES) {
                const float4* p = (const float4*)&x[(size_t)n * NFEAT + c];
                *(float4*)&xs[r][c]     = p[0];
                *(float4*)&xs[r][c + 4] = p[1];
            } else {
                *(float4*)&xs[r][c]     = make_float4(0, 0, 0, 0);
                *(float4*)&xs[r][c + 4] = make_float4(0, 0, 0, 0);
            }
        }
        __syncthreads();
        float a0 = 0.f, a1 = 0.f, a2 = 0.f, a3 = 0.f;
#pragma unroll
        for (int k = 0; k < NFEAT; ++k) {
            float4 w = *(const float4*)&wlds[k * NHID + cg];
            float xv = xs[nl][k];
            a0 += w.x * xv; a1 += w.y * xv; a2 += w.z * xv; a3 += w.w * xv;
        }
        const int n = n0 + nl;
        if (n < N_NODES) {
            union { __half2 h2[2]; uint2 u; } pk;
            pk.h2[0] = __floats2half2_rn(a0, a1);
            pk.h2[1] = __floats2half2_rn(a2, a3);
            *(uint2*)&support[(size_t)n * NHID + cg] = pk.u;
        }
    }
}

// ---------------------------------------------------------------
// bucket build: zero -> hist(LDS) -> scan -> coarse scatter -> fine sort
// ---------------------------------------------------------------
__global__ __launch_bounds__(256) void zero_counts_kernel(int* __restrict__ counts) {
    int i = blockIdx.x * 256 + threadIdx.x;
    if (i < NB) counts[i] = 0;
}

__global__ __launch_bounds__(256) void bucket_hist_kernel(const int* __restrict__ dst,
                                                          int* __restrict__ counts) {
    __shared__ int cnt[NB];
    const int tid = threadIdx.x;
    for (int i = tid; i < NB; i += 256) cnt[i] = 0;
    __syncthreads();
    const int cbase = blockIdx.x * CHUNK;
#pragma unroll
    for (int k = 0; k < CHUNK; k += 256) {
        int e = cbase + k + tid;
        if (e < N_EDGES) atomicAdd(&cnt[dst[e] >> 8], 1);
    }
    __syncthreads();
    for (int i = tid; i < NB; i += 256) {
        int c = cnt[i];
        if (c) atomicAdd(&counts[i], c);
    }
}

__global__ __launch_bounds__(256) void bucket_scan_kernel(const int* __restrict__ counts,
                                                          int* __restrict__ cbase,
                                                          int* __restrict__ cursor) {
    __shared__ int lds[256];
    const int tid = threadIdx.x;
    int v[4]; int tsum = 0;
#pragma unroll
    for (int i = 0; i < 4; ++i) {
        int idx = tid * 4 + i;
        v[i] = (idx < NB) ? counts[idx] : 0;
        tsum += v[i];
    }
    lds[tid] = tsum;
    __syncthreads();
    int val = tsum;
    for (int off = 1; off < 256; off <<= 1) {
        int add = (tid >= off) ? lds[tid - off] : 0;
        __syncthreads();
        val += add;
        lds[tid] = val;
        __syncthreads();
    }
    int excl = val - tsum;
#pragma unroll
    for (int i = 0; i < 4; ++i) {
        int idx = tid * 4 + i;
        if (idx < NB) { cbase[idx] = excl; cursor[idx] = excl; excl += v[i]; }
    }
    if (tid == 255) cbase[NB] = N_EDGES;
}

// record: x = src(17b) | dstLocal(8b)<<17 ; y = val bits
__global__ __launch_bounds__(256) void bucket_scatter_kernel(const float* __restrict__ vals,
                                                             const int* __restrict__ src,
                                                             const int* __restrict__ dst,
                                                             int* __restrict__ cursor,
                                                             uint2* __restrict__ recs) {
    __shared__ int cnt[NB];
    __shared__ int sbase[NB];
    __shared__ int cur[NB];
    __shared__ int gbase[NB];
    __shared__ uint2 rl[CHUNK];                 // 32 KB
    __shared__ unsigned short slotB[CHUNK];     // 8 KB
    __shared__ int scan_lds[256];
    const int tid = threadIdx.x;
    const int cbase0 = blockIdx.x * CHUNK;
    const int m = min(CHUNK, N_EDGES - cbase0);

    for (int i = tid; i < NB; i += 256) cnt[i] = 0;
    int dstv[CHUNK / 256];
    __syncthreads();
#pragma unroll
    for (int k = 0; k < CHUNK / 256; ++k) {
        int e = cbase0 + k * 256 + tid;
        int d = (e < N_EDGES) ? dst[e] : -1;
        dstv[k] = d;
        if (d >= 0) atomicAdd(&cnt[d >> 8], 1);
    }
    __syncthreads();
    {
        int v[4]; int tsum = 0;
#pragma unroll
        for (int i = 0; i < 4; ++i) {
            int idx = tid * 4 + i;
            v[i] = (idx < NB) ? cnt[idx] : 0;
            tsum += v[i];
        }
        scan_lds[tid] = tsum;
        __syncthreads();
        int val = tsum;
        for (int off = 1; off < 256; off <<= 1) {
            int add = (tid >= off) ? scan_lds[tid - off] : 0;
            __syncthreads();
            val += add;
            scan_lds[tid] = val;
            __syncthreads();
        }
        int excl = val - tsum;
#pragma unroll
        for (int i = 0; i < 4; ++i) {
            int idx = tid * 4 + i;
            if (idx < NB) { sbase[idx] = excl; cur[idx] = excl; excl += v[i]; }
        }
    }
    __syncthreads();
    for (int b = tid; b < NB; b += 256) {
        int c = cnt[b];
        gbase[b] = c ? atomicAdd(&cursor[b], c) : 0;
    }
#pragma unroll
    for (int k = 0; k < CHUNK / 256; ++k) {
        int e = cbase0 + k * 256 + tid;
        int d = dstv[k];
        if (d >= 0) {
            int b = d >> 8;
            int slot = atomicAdd(&cur[b], 1);
            rl[slot] = make_uint2((unsigned)src[e] | ((unsigned)(d & (NPB - 1)) << 17),
                                  __float_as_uint(vals[e]));
            slotB[slot] = (unsigned short)b;
        }
    }
    __syncthreads();
    for (int i = tid; i < m; i += 256) {
        int b = slotB[i];
        recs[gbase[b] + (i - sbase[b])] = rl[i];
    }
}

// fine sort: counting-sort each bucket's records into exact node order
__global__ __launch_bounds__(256) void fine_sort_kernel(const int* __restrict__ cbase,
                                                        const uint2* __restrict__ recsC,
                                                        uint2* __restrict__ recs2,
                                                        int* __restrict__ offs) {
    __shared__ int cnt[NPB];
    __shared__ int cur[NPB];
    __shared__ int scan_lds[256];
    const int tid = threadIdx.x;
    const int b = blockIdx.x;
    const int s = cbase[b], e = cbase[b + 1];
    cnt[tid] = 0;
    __syncthreads();
    for (int i = s + tid; i < e; i += 256)
        atomicAdd(&cnt[(recsC[i].x >> 17) & (NPB - 1)], 1);
    __syncthreads();
    int v = cnt[tid];
    scan_lds[tid] = v;
    __syncthreads();
    int val = v;
    for (int off = 1; off < 256; off <<= 1) {
        int add = (tid >= off) ? scan_lds[tid - off] : 0;
        __syncthreads();
        val += add;
        scan_lds[tid] = val;
        __syncthreads();
    }
    int excl = val - v;
    cur[tid] = excl;
    const int node = b * NPB + tid;
    if (node < N_NODES) offs[node] = s + excl;
    if (b == 0 && tid == 0) offs[N_NODES] = N_EDGES;
    __syncthreads();
    for (int i = s + tid; i < e; i += 256) {
        uint2 r = recsC[i];
        int dl = (r.x >> 17) & (NPB - 1);
        int p = atomicAdd(&cur[dl], 1);
        recs2[s + p] = make_uint2(r.x & 0x1FFFF, r.y);
    }
}

// ---------------------------------------------------------------
// SpMM1 (CSR): h[d,:] (fp16) = relu( sum val*support[src,:] + b1 )
// one wave per node, lane = feature (fp16 gather, fp32 accum).
// ---------------------------------------------------------------
__global__ __launch_bounds__(256) void spmm1_csr_kernel(const int* __restrict__ offs,
                                                        const uint2* __restrict__ recs,
                                                        const __half* __restrict__ dense,
                                                        const float* __restrict__ b1,
                                                        __half* __restrict__ h) {
    const int lane = threadIdx.x & 63;
    const int d = (blockIdx.x * 256 + threadIdx.x) >> 6;
    if (d >= N_NODES) return;
    const int start = offs[d], end = offs[d + 1];
    float a0 = 0.f, a1 = 0.f, a2 = 0.f, a3 = 0.f;
    int e = start;
    for (; e + 3 < end; e += 4) {
        uint2 r0 = recs[e], r1 = recs[e + 1], r2 = recs[e + 2], r3 = recs[e + 3];
        a0 += __uint_as_float(r0.y) * __half2float(dense[(size_t)r0.x * NHID + lane]);
        a1 += __uint_as_float(r1.y) * __half2float(dense[(size_t)r1.x * NHID + lane]);
        a2 += __uint_as_float(r2.y) * __half2float(dense[(size_t)r2.x * NHID + lane]);
        a3 += __uint_as_float(r3.y) * __half2float(dense[(size_t)r3.x * NHID + lane]);
    }
    for (; e < end; ++e) {
        uint2 r = recs[e];
        a0 += __uint_as_float(r.y) * __half2float(dense[(size_t)r.x * NHID + lane]);
    }
    float hv = fmaxf((a0 + a1) + (a2 + a3) + b1[lane], 0.f);
    h[(size_t)d * NHID + lane] = __float2half(hv);
}

// ---------------------------------------------------------------
// GEMM2: s2[N,32] (fp16) = h[N,64] (fp16) @ W2[64,32]
// ---------------------------------------------------------------
__global__ __launch_bounds__(256) void gemm2_kernel(const __half* __restrict__ h,
                                                    const float* __restrict__ W2,
                                                    __half* __restrict__ s2) {
    __shared__ float wlds[NHID * NOUT];       // 8 KB
    __shared__ float xs[32][NHID + 1];
    const int tid = threadIdx.x;
    for (int i = tid; i < NHID * NOUT; i += 256) wlds[i] = W2[i];

    const int cg = (tid & 7) * 4;
    const int nl = tid >> 3;                  // 0..31
    const int base = blockIdx.x * 128;

    for (int it = 0; it < 128; it += 32) {
        const int n0 = base + it;
        __syncthreads();
        {   // stage 32 rows x 64 halves: each thread 8 halves (16B load)
            const int r = tid >> 3, c = (tid & 7) * 8;
            const int n = n0 + r;
            if (n < N_NODES) {
                union { float4 f4; __half2 h2[4]; } u;
                u.f4 = *(const float4*)&h[(size_t)n * NHID + c];
#pragma unroll
                for (int j = 0; j < 4; ++j) {
                    float2 f = __half22float2(u.h2[j]);
                    xs[r][c + j * 2]     = f.x;
                    xs[r][c + j * 2 + 1] = f.y;
                }
            } else {
#pragma unroll
                for (int j = 0; j < 8; ++j) xs[r][c + j] = 0.f;
            }
        }
        __syncthreads();
        float a0 = 0.f, a1 = 0.f, a2 = 0.f, a3 = 0.f;
#pragma unroll
        for (int k = 0; k < NHID; ++k) {
            float4 w = *(const float4*)&wlds[k * NOUT + cg];
            float xv = xs[nl][k];
            a0 += w.x * xv; a1 += w.y * xv; a2 += w.z * xv; a3 += w.w * xv;
        }
        const int n = n0 + nl;
        if (n < N_NODES) {
            union { __half2 h2[2]; uint2 u; } pk;
            pk.h2[0] = __floats2half2_rn(a0, a1);
            pk.h2[1] = __floats2half2_rn(a2, a3);
            *(uint2*)&s2[(size_t)n * NOUT + cg] = pk.u;
        }
    }
}

// ---------------------------------------------------------------
// SpMM2 (CSR): out[d,:] (fp32) = sum val*s2[src,:] + b2
// one wave per node; 32-lane halves split edges by parity.
// ---------------------------------------------------------------
__global__ __launch_bounds__(256) void spmm2_csr_kernel(const int* __restrict__ offs,
                                                        const uint2* __restrict__ recs,
                                                        const __half* __restrict__ dense,
                                                        const float* __restrict__ b2,
                                                        float* __restrict__ out) {
    const int lane = threadIdx.x & 63;
    const int half = lane >> 5, l32 = lane & 31;
    const int d = (blockIdx.x * 256 + threadIdx.x) >> 6;
    if (d >= N_NODES) return;
    const int start = offs[d], end = offs[d + 1];
    float a0 = 0.f, a1 = 0.f;
    int e = start + half;
    for (; e + 2 < end; e += 4) {
        uint2 r0 = recs[e], r1 = recs[e + 2];
        a0 += __uint_as_float(r0.y) * __half2float(dense[(size_t)r0.x * NOUT + l32]);
        a1 += __uint_as_float(r1.y) * __half2float(dense[(size_t)r1.x * NOUT + l32]);
    }
    if (e < end) {
        uint2 r = recs[e];
        a0 += __uint_as_float(r.y) * __half2float(dense[(size_t)r.x * NOUT + l32]);
    }
    float acc = a0 + a1;
    acc += __shfl_xor(acc, 32, 64);
    if (half == 0) out[(size_t)d * NOUT + l32] = acc + b2[l32];
}

extern "C" void kernel_launch(void* const* d_in, const int* in_sizes, int n_in,
                              void* d_out, int out_size, void* d_ws, size_t ws_size,
                              hipStream_t stream) {
    const float* x        = (const float*)d_in[0];
    const float* adj_vals = (const float*)d_in[1];
    const float* W1       = (const float*)d_in[2];
    const float* b1       = (const float*)d_in[3];
    const float* W2       = (const float*)d_in[4];
    const float* b2       = (const float*)d_in[5];
    const int*   esrc     = (const int*)d_in[6];
    const int*   edst     = (const int*)d_in[7];
    float*       out      = (float*)d_out;

    // ws layout (~51.2 MB, all rewritten every call):
    //   support[6.4M half = 12.8MB]  (s2 aliases: support dead after spmm1)
    //   h[6.4M half = 12.8MB]        (coarse recs alias h: dead before h write)
    //   recs2[1.6M uint2 = 12.8MB] | offs[N+1] | counts | cbase | cursor
    char* W = (char*)d_ws;
    __half* support = (__half*)W;
    __half* h       = (__half*)(W + 12800000);
    uint2*  recsC   = (uint2*)h;
    uint2*  recs2   = (uint2*)(W + 25600000);
    int*    offs    = (int*)(W + 38400000);                // N+1
    int*    counts  = offs + (N_NODES + 2);
    int*    cbase   = counts + 512;                        // NB+1
    int*    cursor  = cbase + 512;                         // NB
    __half* s2      = support;

    // 1. support = x @ W1
    gemm1_kernel<<<(N_NODES + 63) / 64, 256, 0, stream>>>(x, W1, support);

    // 2. bucket CSR build (shared by both SpMMs)
    zero_counts_kernel<<<(NB + 255) / 256, 256, 0, stream>>>(counts);
    bucket_hist_kernel<<<NCHUNK, 256, 0, stream>>>(edst, counts);
    bucket_scan_kernel<<<1, 256, 0, stream>>>(counts, cbase, cursor);
    bucket_scatter_kernel<<<NCHUNK, 256, 0, stream>>>(adj_vals, esrc, edst, cursor, recsC);
    fine_sort_kernel<<<NB, 256, 0, stream>>>(cbase, recsC, recs2, offs);

    // 3. h = relu(A @ support + b1)   (overwrites recsC region — recsC dead)
    spmm1_csr_kernel<<<(N_NODES * 64 + 255) / 256, 256, 0, stream>>>(offs, recs2,
                                                                     support, b1, h);

    // 4. s2 = h @ W2  (into support region)
    gemm2_kernel<<<(N_NODES + 127) / 128, 256, 0, stream>>>(h, W2, s2);

    // 5. out = A @ s2 + b2
    spmm2_csr_kernel<<<(N_NODES * 64 + 255) / 256, 256, 0, stream>>>(offs, recs2,
                                                                     s2, b2, out);
}

// Round 6
// 229.040 us; speedup vs baseline: 5.2061x; 1.1338x over previous
//
#include <hip/hip_runtime.h>
#include <hip/hip_fp16.h>

#define N_NODES 100000
#define N_EDGES 1600000
#define NFEAT 128
#define NHID 64
#define NOUT 32

#define NPB 256                                  // nodes per bucket (dst >> 8)
#define NB ((N_NODES + NPB - 1) / NPB)           // 391 buckets
#define CHUNK 4096                               // edges per scatter/hist block
#define NCHUNK ((N_EDGES + CHUNK - 1) / CHUNK)   // 391

// ---------------------------------------------------------------
// GEMM1: support[N,64] (fp16) = x[N,128] @ W1[128,64]
// ---------------------------------------------------------------
__global__ __launch_bounds__(256) void gemm1_kernel(const float* __restrict__ x,
                                                    const float* __restrict__ W1,
                                                    __half* __restrict__ support) {
    __shared__ float wlds[NFEAT * NHID];      // 32 KB, [k][col]
    __shared__ float xs[16][NFEAT + 1];
    const int tid = threadIdx.x;
    for (int i = tid; i < NFEAT * NHID; i += 256) wlds[i] = W1[i];

    const int cg = (tid & 15) * 4;            // col group (0,4,..,60)
    const int nl = tid >> 4;                  // node-in-tile 0..15
    const int base = blockIdx.x * 64;

    for (int it = 0; it < 64; it += 16) {
        const int n0 = base + it;
        __syncthreads();
        {
            const int r = tid >> 4, c = (tid & 15) * 8;
            const int n = n0 + r;
            if (n < N_NODES) {
                const float4* p = (const float4*)&x[(size_t)n * NFEAT + c];
                *(float4*)&xs[r][c]     = p[0];
                *(float4*)&xs[r][c + 4] = p[1];
            } else {
                *(float4*)&xs[r][c]     = make_float4(0, 0, 0, 0);
                *(float4*)&xs[r][c + 4] = make_float4(0, 0, 0, 0);
            }
        }
        __syncthreads();
        float a0 = 0.f, a1 = 0.f, a2 = 0.f, a3 = 0.f;
#pragma unroll
        for (int k = 0; k < NFEAT; ++k) {
            float4 w = *(const float4*)&wlds[k * NHID + cg];
            float xv = xs[nl][k];
            a0 += w.x * xv; a1 += w.y * xv; a2 += w.z * xv; a3 += w.w * xv;
        }
        const int n = n0 + nl;
        if (n < N_NODES) {
            union { __half2 h2[2]; uint2 u; } pk;
            pk.h2[0] = __floats2half2_rn(a0, a1);
            pk.h2[1] = __floats2half2_rn(a2, a3);
            *(uint2*)&support[(size_t)n * NHID + cg] = pk.u;
        }
    }
}

// ---------------------------------------------------------------
// bucket build: zero -> hist(LDS) -> scan -> coarse scatter -> fine sort
// ---------------------------------------------------------------
__global__ __launch_bounds__(256) void zero_counts_kernel(int* __restrict__ counts) {
    int i = blockIdx.x * 256 + threadIdx.x;
    if (i < NB) counts[i] = 0;
}

__global__ __launch_bounds__(256) void bucket_hist_kernel(const int* __restrict__ dst,
                                                          int* __restrict__ counts) {
    __shared__ int cnt[NB];
    const int tid = threadIdx.x;
    for (int i = tid; i < NB; i += 256) cnt[i] = 0;
    __syncthreads();
    const int cbase = blockIdx.x * CHUNK;
#pragma unroll
    for (int k = 0; k < CHUNK; k += 256) {
        int e = cbase + k + tid;
        if (e < N_EDGES) atomicAdd(&cnt[dst[e] >> 8], 1);
    }
    __syncthreads();
    for (int i = tid; i < NB; i += 256) {
        int c = cnt[i];
        if (c) atomicAdd(&counts[i], c);
    }
}

__global__ __launch_bounds__(256) void bucket_scan_kernel(const int* __restrict__ counts,
                                                          int* __restrict__ cbase,
                                                          int* __restrict__ cursor) {
    __shared__ int lds[256];
    const int tid = threadIdx.x;
    int v[4]; int tsum = 0;
#pragma unroll
    for (int i = 0; i < 4; ++i) {
        int idx = tid * 4 + i;
        v[i] = (idx < NB) ? counts[idx] : 0;
        tsum += v[i];
    }
    lds[tid] = tsum;
    __syncthreads();
    int val = tsum;
    for (int off = 1; off < 256; off <<= 1) {
        int add = (tid >= off) ? lds[tid - off] : 0;
        __syncthreads();
        val += add;
        lds[tid] = val;
        __syncthreads();
    }
    int excl = val - tsum;
#pragma unroll
    for (int i = 0; i < 4; ++i) {
        int idx = tid * 4 + i;
        if (idx < NB) { cbase[idx] = excl; cursor[idx] = excl; excl += v[i]; }
    }
    if (tid == 255) cbase[NB] = N_EDGES;
}

// record: x = src(17b) | dstLocal(8b)<<17 ; y = val bits
__global__ __launch_bounds__(256) void bucket_scatter_kernel(const float* __restrict__ vals,
                                                             const int* __restrict__ src,
                                                             const int* __restrict__ dst,
                                                             int* __restrict__ cursor,
                                                             uint2* __restrict__ recs) {
    __shared__ int cnt[NB];
    __shared__ int sbase[NB];
    __shared__ int cur[NB];
    __shared__ int gbase[NB];
    __shared__ uint2 rl[CHUNK];                 // 32 KB
    __shared__ unsigned short slotB[CHUNK];     // 8 KB
    __shared__ int scan_lds[256];
    const int tid = threadIdx.x;
    const int cbase0 = blockIdx.x * CHUNK;
    const int m = min(CHUNK, N_EDGES - cbase0);

    for (int i = tid; i < NB; i += 256) cnt[i] = 0;
    int dstv[CHUNK / 256];
    __syncthreads();
#pragma unroll
    for (int k = 0; k < CHUNK / 256; ++k) {
        int e = cbase0 + k * 256 + tid;
        int d = (e < N_EDGES) ? dst[e] : -1;
        dstv[k] = d;
        if (d >= 0) atomicAdd(&cnt[d >> 8], 1);
    }
    __syncthreads();
    {
        int v[4]; int tsum = 0;
#pragma unroll
        for (int i = 0; i < 4; ++i) {
            int idx = tid * 4 + i;
            v[i] = (idx < NB) ? cnt[idx] : 0;
            tsum += v[i];
        }
        scan_lds[tid] = tsum;
        __syncthreads();
        int val = tsum;
        for (int off = 1; off < 256; off <<= 1) {
            int add = (tid >= off) ? scan_lds[tid - off] : 0;
            __syncthreads();
            val += add;
            scan_lds[tid] = val;
            __syncthreads();
        }
        int excl = val - tsum;
#pragma unroll
        for (int i = 0; i < 4; ++i) {
            int idx = tid * 4 + i;
            if (idx < NB) { sbase[idx] = excl; cur[idx] = excl; excl += v[i]; }
        }
    }
    __syncthreads();
    for (int b = tid; b < NB; b += 256) {
        int c = cnt[b];
        gbase[b] = c ? atomicAdd(&cursor[b], c) : 0;
    }
#pragma unroll
    for (int k = 0; k < CHUNK / 256; ++k) {
        int e = cbase0 + k * 256 + tid;
        int d = dstv[k];
        if (d >= 0) {
            int b = d >> 8;
            int slot = atomicAdd(&cur[b], 1);
            rl[slot] = make_uint2((unsigned)src[e] | ((unsigned)(d & (NPB - 1)) << 17),
                                  __float_as_uint(vals[e]));
            slotB[slot] = (unsigned short)b;
        }
    }
    __syncthreads();
    for (int i = tid; i < m; i += 256) {
        int b = slotB[i];
        recs[gbase[b] + (i - sbase[b])] = rl[i];
    }
}

// fine sort: counting-sort each bucket's records into exact node order
__global__ __launch_bounds__(256) void fine_sort_kernel(const int* __restrict__ cbase,
                                                        const uint2* __restrict__ recsC,
                                                        uint2* __restrict__ recs2,
                                                        int* __restrict__ offs) {
    __shared__ int cnt[NPB];
    __shared__ int cur[NPB];
    __shared__ int scan_lds[256];
    const int tid = threadIdx.x;
    const int b = blockIdx.x;
    const int s = cbase[b], e = cbase[b + 1];
    cnt[tid] = 0;
    __syncthreads();
    for (int i = s + tid; i < e; i += 256)
        atomicAdd(&cnt[(recsC[i].x >> 17) & (NPB - 1)], 1);
    __syncthreads();
    int v = cnt[tid];
    scan_lds[tid] = v;
    __syncthreads();
    int val = v;
    for (int off = 1; off < 256; off <<= 1) {
        int add = (tid >= off) ? scan_lds[tid - off] : 0;
        __syncthreads();
        val += add;
        scan_lds[tid] = val;
        __syncthreads();
    }
    int excl = val - v;
    cur[tid] = excl;
    const int node = b * NPB + tid;
    if (node < N_NODES) offs[node] = s + excl;
    if (b == 0 && tid == 0) offs[N_NODES] = N_EDGES;
    __syncthreads();
    for (int i = s + tid; i < e; i += 256) {
        uint2 r = recsC[i];
        int dl = (r.x >> 17) & (NPB - 1);
        int p = atomicAdd(&cur[dl], 1);
        recs2[s + p] = make_uint2(r.x & 0x1FFFF, r.y);
    }
}

// ---------------------------------------------------------------
// SpMM1 (CSR): h[d,:] (fp16) = relu( sum val*support[src,:] + b1 )
// one wave per node, lane = feature.
// Records loaded COALESCED (lane l -> rec start+l), then broadcast via
// readlane (SALU, uniform idx) -> gathers have no VMEM dependence and
// all ~deg(d) of them stay in flight.
// ---------------------------------------------------------------
__global__ __launch_bounds__(256) void spmm1_csr_kernel(const int* __restrict__ offs,
                                                        const uint2* __restrict__ recs,
                                                        const __half* __restrict__ dense,
                                                        const float* __restrict__ b1,
                                                        __half* __restrict__ h) {
    const int lane = threadIdx.x & 63;
    const int d = (blockIdx.x * 256 + threadIdx.x) >> 6;
    if (d >= N_NODES) return;
    const int start = offs[d], end = offs[d + 1];
    const int cnt = end - start;
    float a0 = 0.f, a1 = 0.f, a2 = 0.f, a3 = 0.f;
    for (int cb = 0; cb < cnt; cb += 64) {
        const int rem = min(64, cnt - cb);
        uint2 myrec = make_uint2(0u, 0u);
        if (lane < rem) myrec = recs[start + cb + lane];
        int e = 0;
        for (; e + 3 < rem; e += 4) {
            unsigned s0 = __builtin_amdgcn_readlane(myrec.x, e);
            unsigned s1 = __builtin_amdgcn_readlane(myrec.x, e + 1);
            unsigned s2 = __builtin_amdgcn_readlane(myrec.x, e + 2);
            unsigned s3 = __builtin_amdgcn_readlane(myrec.x, e + 3);
            float v0 = __uint_as_float(__builtin_amdgcn_readlane(myrec.y, e));
            float v1 = __uint_as_float(__builtin_amdgcn_readlane(myrec.y, e + 1));
            float v2 = __uint_as_float(__builtin_amdgcn_readlane(myrec.y, e + 2));
            float v3 = __uint_as_float(__builtin_amdgcn_readlane(myrec.y, e + 3));
            a0 += v0 * __half2float(dense[(size_t)s0 * NHID + lane]);
            a1 += v1 * __half2float(dense[(size_t)s1 * NHID + lane]);
            a2 += v2 * __half2float(dense[(size_t)s2 * NHID + lane]);
            a3 += v3 * __half2float(dense[(size_t)s3 * NHID + lane]);
        }
        for (; e < rem; ++e) {
            unsigned s0 = __builtin_amdgcn_readlane(myrec.x, e);
            float v0 = __uint_as_float(__builtin_amdgcn_readlane(myrec.y, e));
            a0 += v0 * __half2float(dense[(size_t)s0 * NHID + lane]);
        }
    }
    float hv = fmaxf((a0 + a1) + (a2 + a3) + b1[lane], 0.f);
    h[(size_t)d * NHID + lane] = __float2half(hv);
}

// ---------------------------------------------------------------
// SpMM2 (CSR): out[d,:] (fp32) = sum val*s2[src,:] + b2
// one wave per node; halves take even/odd edges (uniform control flow,
// per-half record selected with cndmask from readlane-broadcast SGPRs).
// ---------------------------------------------------------------
__global__ __launch_bounds__(256) void spmm2_csr_kernel(const int* __restrict__ offs,
                                                        const uint2* __restrict__ recs,
                                                        const __half* __restrict__ dense,
                                                        const float* __restrict__ b2,
                                                        float* __restrict__ out) {
    const int lane = threadIdx.x & 63;
    const int half = lane >> 5, l32 = lane & 31;
    const int d = (blockIdx.x * 256 + threadIdx.x) >> 6;
    if (d >= N_NODES) return;
    const int start = offs[d], end = offs[d + 1];
    const int cnt = end - start;
    float a0 = 0.f, a1 = 0.f;
    for (int cb = 0; cb < cnt; cb += 64) {
        const int rem = min(64, cnt - cb);
        uint2 myrec = make_uint2(0u, 0u);
        if (lane < rem) myrec = recs[start + cb + lane];
        int e = 0;
        for (; e + 3 < rem; e += 4) {
            unsigned sa0 = __builtin_amdgcn_readlane(myrec.x, e);
            unsigned sb0 = __builtin_amdgcn_readlane(myrec.x, e + 1);
            unsigned sa1 = __builtin_amdgcn_readlane(myrec.x, e + 2);
            unsigned sb1 = __builtin_amdgcn_readlane(myrec.x, e + 3);
            float va0 = __uint_as_float(__builtin_amdgcn_readlane(myrec.y, e));
            float vb0 = __uint_as_float(__builtin_amdgcn_readlane(myrec.y, e + 1));
            float va1 = __uint_as_float(__builtin_amdgcn_readlane(myrec.y, e + 2));
            float vb1 = __uint_as_float(__builtin_amdgcn_readlane(myrec.y, e + 3));
            unsigned s0 = half ? sb0 : sa0;  float v0 = half ? vb0 : va0;
            unsigned s1 = half ? sb1 : sa1;  float v1 = half ? vb1 : va1;
            a0 += v0 * __half2float(dense[(size_t)s0 * NOUT + l32]);
            a1 += v1 * __half2float(dense[(size_t)s1 * NOUT + l32]);
        }
        for (; e < rem; e += 2) {
            unsigned sa = __builtin_amdgcn_readlane(myrec.x, e);
            float va = __uint_as_float(__builtin_amdgcn_readlane(myrec.y, e));
            if (e + 1 < rem) {
                unsigned sb = __builtin_amdgcn_readlane(myrec.x, e + 1);
                float vb = __uint_as_float(__builtin_amdgcn_readlane(myrec.y, e + 1));
                unsigned s = half ? sb : sa;  float v = half ? vb : va;
                a0 += v * __half2float(dense[(size_t)s * NOUT + l32]);
            } else if (half == 0) {
                a0 += va * __half2float(dense[(size_t)sa * NOUT + l32]);
            }
        }
    }
    float acc = a0 + a1;
    acc += __shfl_xor(acc, 32, 64);
    if (half == 0) out[(size_t)d * NOUT + l32] = acc + b2[l32];
}

// ---------------------------------------------------------------
// GEMM2: s2[N,32] (fp16) = h[N,64] (fp16) @ W2[64,32]
// ---------------------------------------------------------------
__global__ __launch_bounds__(256) void gemm2_kernel(const __half* __restrict__ h,
                                                    const float* __restrict__ W2,
                                                    __half* __restrict__ s2) {
    __shared__ float wlds[NHID * NOUT];       // 8 KB
    __shared__ float xs[32][NHID + 1];
    const int tid = threadIdx.x;
    for (int i = tid; i < NHID * NOUT; i += 256) wlds[i] = W2[i];

    const int cg = (tid & 7) * 4;
    const int nl = tid >> 3;                  // 0..31
    const int base = blockIdx.x * 128;

    for (int it = 0; it < 128; it += 32) {
        const int n0 = base + it;
        __syncthreads();
        {
            const int r = tid >> 3, c = (tid & 7) * 8;
            const int n = n0 + r;
            if (n < N_NODES) {
                union { float4 f4; __half2 h2[4]; } u;
                u.f4 = *(const float4*)&h[(size_t)n * NHID + c];
#pragma unroll
                for (int j = 0; j < 4; ++j) {
                    float2 f = __half22float2(u.h2[j]);
                    xs[r][c + j * 2]     = f.x;
                    xs[r][c + j * 2 + 1] = f.y;
                }
            } else {
#pragma unroll
                for (int j = 0; j < 8; ++j) xs[r][c + j] = 0.f;
            }
        }
        __syncthreads();
        float a0 = 0.f, a1 = 0.f, a2 = 0.f, a3 = 0.f;
#pragma unroll
        for (int k = 0; k < NHID; ++k) {
            float4 w = *(const float4*)&wlds[k * NOUT + cg];
            float xv = xs[nl][k];
            a0 += w.x * xv; a1 += w.y * xv; a2 += w.z * xv; a3 += w.w * xv;
        }
        const int n = n0 + nl;
        if (n < N_NODES) {
            union { __half2 h2[2]; uint2 u; } pk;
            pk.h2[0] = __floats2half2_rn(a0, a1);
            pk.h2[1] = __floats2half2_rn(a2, a3);
            *(uint2*)&s2[(size_t)n * NOUT + cg] = pk.u;
        }
    }
}

extern "C" void kernel_launch(void* const* d_in, const int* in_sizes, int n_in,
                              void* d_out, int out_size, void* d_ws, size_t ws_size,
                              hipStream_t stream) {
    const float* x        = (const float*)d_in[0];
    const float* adj_vals = (const float*)d_in[1];
    const float* W1       = (const float*)d_in[2];
    const float* b1       = (const float*)d_in[3];
    const float* W2       = (const float*)d_in[4];
    const float* b2       = (const float*)d_in[5];
    const int*   esrc     = (const int*)d_in[6];
    const int*   edst     = (const int*)d_in[7];
    float*       out      = (float*)d_out;

    // ws layout (~38.8 MB used, all rewritten every call):
    //   support[6.4M half = 12.8MB]  (s2 aliases: support dead after spmm1)
    //   h[6.4M half = 12.8MB]        (coarse recs alias h: dead before h write)
    //   recs2[1.6M uint2 = 12.8MB] | offs[N+1] | counts | cbase | cursor
    char* W = (char*)d_ws;
    __half* support = (__half*)W;
    __half* h       = (__half*)(W + 12800000);
    uint2*  recsC   = (uint2*)h;
    uint2*  recs2   = (uint2*)(W + 25600000);
    int*    offs    = (int*)(W + 38400000);                // N+1
    int*    counts  = offs + (N_NODES + 2);
    int*    cbase   = counts + 512;                        // NB+1
    int*    cursor  = cbase + 512;                         // NB
    __half* s2      = support;

    // 1. support = x @ W1
    gemm1_kernel<<<(N_NODES + 63) / 64, 256, 0, stream>>>(x, W1, support);

    // 2. bucket CSR build (shared by both SpMMs)
    zero_counts_kernel<<<(NB + 255) / 256, 256, 0, stream>>>(counts);
    bucket_hist_kernel<<<NCHUNK, 256, 0, stream>>>(edst, counts);
    bucket_scan_kernel<<<1, 256, 0, stream>>>(counts, cbase, cursor);
    bucket_scatter_kernel<<<NCHUNK, 256, 0, stream>>>(adj_vals, esrc, edst, cursor, recsC);
    fine_sort_kernel<<<NB, 256, 0, stream>>>(cbase, recsC, recs2, offs);

    // 3. h = relu(A @ support + b1)   (overwrites recsC region — recsC dead)
    spmm1_csr_kernel<<<(N_NODES * 64 + 255) / 256, 256, 0, stream>>>(offs, recs2,
                                                                     support, b1, h);

    // 4. s2 = h @ W2  (into support region)
    gemm2_kernel<<<(N_NODES + 127) / 128, 256, 0, stream>>>(h, W2, s2);

    // 5. out = A @ s2 + b2
    spmm2_csr_kernel<<<(N_NODES * 64 + 255) / 256, 256, 0, stream>>>(offs, recs2,
                                                                     s2, b2, out);
}

// Round 7
// 206.186 us; speedup vs baseline: 5.7832x; 1.1108x over previous
//
#include <hip/hip_runtime.h>
#include <hip/hip_fp16.h>

#define N_NODES 100000
#define N_EDGES 1600000
#define NFEAT 128
#define NHID 64
#define NOUT 32

#define NPB 256                                  // nodes per bucket (dst >> 8)
#define NB ((N_NODES + NPB - 1) / NPB)           // 391 buckets
#define CHUNK 4096                               // edges per scatter/hist block
#define NCHUNK ((N_EDGES + CHUNK - 1) / CHUNK)   // 391

// ---------------------------------------------------------------
// GEMM1: support[N,64] (fp16) = x[N,128] @ W1[128,64]
// Register-blocked 4 nodes x 4 cols per thread; W1 in LDS (broadcast),
// x streamed from global (L1-line reuse across k). No staging sync,
// no bank conflicts: 0.5 LDS-B/FLOP -> VALU-bound.
// ---------------------------------------------------------------
__global__ __launch_bounds__(256) void gemm1_kernel(const float* __restrict__ x,
                                                    const float* __restrict__ W1,
                                                    __half* __restrict__ support) {
    __shared__ float wlds[NFEAT * NHID];      // 32 KB, [k][col]
    const int tid = threadIdx.x;
    for (int i = tid; i < NFEAT * NHID; i += 256) wlds[i] = W1[i];

    const int cg = (tid & 15) * 4;            // col group: 4 cols
    const int ng = tid >> 4;                  // node group 0..15
    const int n0 = blockIdx.x * 64 + ng * 4;  // 4 nodes per thread

    int nidx[4];
#pragma unroll
    for (int i = 0; i < 4; ++i) {
        int n = n0 + i;
        nidx[i] = (n < N_NODES) ? n : (N_NODES - 1);   // clamp (store guarded)
    }
    __syncthreads();

    float acc[4][4];
#pragma unroll
    for (int i = 0; i < 4; ++i)
#pragma unroll
        for (int j = 0; j < 4; ++j) acc[i][j] = 0.f;

    for (int k0 = 0; k0 < NFEAT; k0 += 4) {
        float4 xr[4];
#pragma unroll
        for (int i = 0; i < 4; ++i)
            xr[i] = *(const float4*)&x[(size_t)nidx[i] * NFEAT + k0];
#pragma unroll
        for (int kk = 0; kk < 4; ++kk) {
            float4 w = *(const float4*)&wlds[(k0 + kk) * NHID + cg];
#pragma unroll
            for (int i = 0; i < 4; ++i) {
                float xv = (&xr[i].x)[kk];
                acc[i][0] += w.x * xv; acc[i][1] += w.y * xv;
                acc[i][2] += w.z * xv; acc[i][3] += w.w * xv;
            }
        }
    }
#pragma unroll
    for (int i = 0; i < 4; ++i) {
        int n = n0 + i;
        if (n < N_NODES) {
            union { __half2 h2[2]; uint2 u; } pk;
            pk.h2[0] = __floats2half2_rn(acc[i][0], acc[i][1]);
            pk.h2[1] = __floats2half2_rn(acc[i][2], acc[i][3]);
            *(uint2*)&support[(size_t)n * NHID + cg] = pk.u;
        }
    }
}

// ---------------------------------------------------------------
// bucket build: zero -> hist(LDS) -> scan -> coarse scatter -> fine sort
// ---------------------------------------------------------------
__global__ __launch_bounds__(256) void zero_counts_kernel(int* __restrict__ counts) {
    int i = blockIdx.x * 256 + threadIdx.x;
    if (i < NB) counts[i] = 0;
}

__global__ __launch_bounds__(256) void bucket_hist_kernel(const int* __restrict__ dst,
                                                          int* __restrict__ counts) {
    __shared__ int cnt[NB];
    const int tid = threadIdx.x;
    for (int i = tid; i < NB; i += 256) cnt[i] = 0;
    __syncthreads();
    const int cbase = blockIdx.x * CHUNK;
#pragma unroll
    for (int k = 0; k < CHUNK; k += 256) {
        int e = cbase + k + tid;
        if (e < N_EDGES) atomicAdd(&cnt[dst[e] >> 8], 1);
    }
    __syncthreads();
    for (int i = tid; i < NB; i += 256) {
        int c = cnt[i];
        if (c) atomicAdd(&counts[i], c);
    }
}

__global__ __launch_bounds__(256) void bucket_scan_kernel(const int* __restrict__ counts,
                                                          int* __restrict__ cbase,
                                                          int* __restrict__ cursor) {
    __shared__ int lds[256];
    const int tid = threadIdx.x;
    int v[4]; int tsum = 0;
#pragma unroll
    for (int i = 0; i < 4; ++i) {
        int idx = tid * 4 + i;
        v[i] = (idx < NB) ? counts[idx] : 0;
        tsum += v[i];
    }
    lds[tid] = tsum;
    __syncthreads();
    int val = tsum;
    for (int off = 1; off < 256; off <<= 1) {
        int add = (tid >= off) ? lds[tid - off] : 0;
        __syncthreads();
        val += add;
        lds[tid] = val;
        __syncthreads();
    }
    int excl = val - tsum;
#pragma unroll
    for (int i = 0; i < 4; ++i) {
        int idx = tid * 4 + i;
        if (idx < NB) { cbase[idx] = excl; cursor[idx] = excl; excl += v[i]; }
    }
    if (tid == 255) cbase[NB] = N_EDGES;
}

// record: x = src(17b) | dstLocal(8b)<<17 ; y = val bits
__global__ __launch_bounds__(256) void bucket_scatter_kernel(const float* __restrict__ vals,
                                                             const int* __restrict__ src,
                                                             const int* __restrict__ dst,
                                                             int* __restrict__ cursor,
                                                             uint2* __restrict__ recs) {
    __shared__ int cnt[NB];
    __shared__ int sbase[NB];
    __shared__ int cur[NB];
    __shared__ int gbase[NB];
    __shared__ uint2 rl[CHUNK];                 // 32 KB
    __shared__ unsigned short slotB[CHUNK];     // 8 KB
    __shared__ int scan_lds[256];
    const int tid = threadIdx.x;
    const int cbase0 = blockIdx.x * CHUNK;
    const int m = min(CHUNK, N_EDGES - cbase0);

    for (int i = tid; i < NB; i += 256) cnt[i] = 0;
    int dstv[CHUNK / 256];
    __syncthreads();
#pragma unroll
    for (int k = 0; k < CHUNK / 256; ++k) {
        int e = cbase0 + k * 256 + tid;
        int d = (e < N_EDGES) ? dst[e] : -1;
        dstv[k] = d;
        if (d >= 0) atomicAdd(&cnt[d >> 8], 1);
    }
    __syncthreads();
    {
        int v[4]; int tsum = 0;
#pragma unroll
        for (int i = 0; i < 4; ++i) {
            int idx = tid * 4 + i;
            v[i] = (idx < NB) ? cnt[idx] : 0;
            tsum += v[i];
        }
        scan_lds[tid] = tsum;
        __syncthreads();
        int val = tsum;
        for (int off = 1; off < 256; off <<= 1) {
            int add = (tid >= off) ? scan_lds[tid - off] : 0;
            __syncthreads();
            val += add;
            scan_lds[tid] = val;
            __syncthreads();
        }
        int excl = val - tsum;
#pragma unroll
        for (int i = 0; i < 4; ++i) {
            int idx = tid * 4 + i;
            if (idx < NB) { sbase[idx] = excl; cur[idx] = excl; excl += v[i]; }
        }
    }
    __syncthreads();
    for (int b = tid; b < NB; b += 256) {
        int c = cnt[b];
        gbase[b] = c ? atomicAdd(&cursor[b], c) : 0;
    }
#pragma unroll
    for (int k = 0; k < CHUNK / 256; ++k) {
        int e = cbase0 + k * 256 + tid;
        int d = dstv[k];
        if (d >= 0) {
            int b = d >> 8;
            int slot = atomicAdd(&cur[b], 1);
            rl[slot] = make_uint2((unsigned)src[e] | ((unsigned)(d & (NPB - 1)) << 17),
                                  __float_as_uint(vals[e]));
            slotB[slot] = (unsigned short)b;
        }
    }
    __syncthreads();
    for (int i = tid; i < m; i += 256) {
        int b = slotB[i];
        recs[gbase[b] + (i - sbase[b])] = rl[i];
    }
}

// fine sort: counting-sort each bucket's records into exact node order
__global__ __launch_bounds__(256) void fine_sort_kernel(const int* __restrict__ cbase,
                                                        const uint2* __restrict__ recsC,
                                                        uint2* __restrict__ recs2,
                                                        int* __restrict__ offs) {
    __shared__ int cnt[NPB];
    __shared__ int cur[NPB];
    __shared__ int scan_lds[256];
    const int tid = threadIdx.x;
    const int b = blockIdx.x;
    const int s = cbase[b], e = cbase[b + 1];
    cnt[tid] = 0;
    __syncthreads();
    for (int i = s + tid; i < e; i += 256)
        atomicAdd(&cnt[(recsC[i].x >> 17) & (NPB - 1)], 1);
    __syncthreads();
    int v = cnt[tid];
    scan_lds[tid] = v;
    __syncthreads();
    int val = v;
    for (int off = 1; off < 256; off <<= 1) {
        int add = (tid >= off) ? scan_lds[tid - off] : 0;
        __syncthreads();
        val += add;
        scan_lds[tid] = val;
        __syncthreads();
    }
    int excl = val - v;
    cur[tid] = excl;
    const int node = b * NPB + tid;
    if (node < N_NODES) offs[node] = s + excl;
    if (b == 0 && tid == 0) offs[N_NODES] = N_EDGES;
    __syncthreads();
    for (int i = s + tid; i < e; i += 256) {
        uint2 r = recsC[i];
        int dl = (r.x >> 17) & (NPB - 1);
        int p = atomicAdd(&cur[dl], 1);
        recs2[s + p] = make_uint2(r.x & 0x1FFFF, r.y);
    }
}

// ---------------------------------------------------------------
// SpMM1 (CSR): h[d,:] (fp16) = relu( sum val*support[src,:] + b1 )
// one wave per node; records loaded coalesced, broadcast via readlane.
// ---------------------------------------------------------------
__global__ __launch_bounds__(256) void spmm1_csr_kernel(const int* __restrict__ offs,
                                                        const uint2* __restrict__ recs,
                                                        const __half* __restrict__ dense,
                                                        const float* __restrict__ b1,
                                                        __half* __restrict__ h) {
    const int lane = threadIdx.x & 63;
    const int d = (blockIdx.x * 256 + threadIdx.x) >> 6;
    if (d >= N_NODES) return;
    const int start = offs[d], end = offs[d + 1];
    const int cnt = end - start;
    float a0 = 0.f, a1 = 0.f, a2 = 0.f, a3 = 0.f;
    for (int cb = 0; cb < cnt; cb += 64) {
        const int rem = min(64, cnt - cb);
        uint2 myrec = make_uint2(0u, 0u);
        if (lane < rem) myrec = recs[start + cb + lane];
        int e = 0;
        for (; e + 3 < rem; e += 4) {
            unsigned s0 = __builtin_amdgcn_readlane(myrec.x, e);
            unsigned s1 = __builtin_amdgcn_readlane(myrec.x, e + 1);
            unsigned s2 = __builtin_amdgcn_readlane(myrec.x, e + 2);
            unsigned s3 = __builtin_amdgcn_readlane(myrec.x, e + 3);
            float v0 = __uint_as_float(__builtin_amdgcn_readlane(myrec.y, e));
            float v1 = __uint_as_float(__builtin_amdgcn_readlane(myrec.y, e + 1));
            float v2 = __uint_as_float(__builtin_amdgcn_readlane(myrec.y, e + 2));
            float v3 = __uint_as_float(__builtin_amdgcn_readlane(myrec.y, e + 3));
            a0 += v0 * __half2float(dense[(size_t)s0 * NHID + lane]);
            a1 += v1 * __half2float(dense[(size_t)s1 * NHID + lane]);
            a2 += v2 * __half2float(dense[(size_t)s2 * NHID + lane]);
            a3 += v3 * __half2float(dense[(size_t)s3 * NHID + lane]);
        }
        for (; e < rem; ++e) {
            unsigned s0 = __builtin_amdgcn_readlane(myrec.x, e);
            float v0 = __uint_as_float(__builtin_amdgcn_readlane(myrec.y, e));
            a0 += v0 * __half2float(dense[(size_t)s0 * NHID + lane]);
        }
    }
    float hv = fmaxf((a0 + a1) + (a2 + a3) + b1[lane], 0.f);
    h[(size_t)d * NHID + lane] = __float2half(hv);
}

// ---------------------------------------------------------------
// SpMM2 (CSR): out[d,:] (fp32) = sum val*s2[src,:] + b2
// ---------------------------------------------------------------
__global__ __launch_bounds__(256) void spmm2_csr_kernel(const int* __restrict__ offs,
                                                        const uint2* __restrict__ recs,
                                                        const __half* __restrict__ dense,
                                                        const float* __restrict__ b2,
                                                        float* __restrict__ out) {
    const int lane = threadIdx.x & 63;
    const int half = lane >> 5, l32 = lane & 31;
    const int d = (blockIdx.x * 256 + threadIdx.x) >> 6;
    if (d >= N_NODES) return;
    const int start = offs[d], end = offs[d + 1];
    const int cnt = end - start;
    float a0 = 0.f, a1 = 0.f;
    for (int cb = 0; cb < cnt; cb += 64) {
        const int rem = min(64, cnt - cb);
        uint2 myrec = make_uint2(0u, 0u);
        if (lane < rem) myrec = recs[start + cb + lane];
        int e = 0;
        for (; e + 3 < rem; e += 4) {
            unsigned sa0 = __builtin_amdgcn_readlane(myrec.x, e);
            unsigned sb0 = __builtin_amdgcn_readlane(myrec.x, e + 1);
            unsigned sa1 = __builtin_amdgcn_readlane(myrec.x, e + 2);
            unsigned sb1 = __builtin_amdgcn_readlane(myrec.x, e + 3);
            float va0 = __uint_as_float(__builtin_amdgcn_readlane(myrec.y, e));
            float vb0 = __uint_as_float(__builtin_amdgcn_readlane(myrec.y, e + 1));
            float va1 = __uint_as_float(__builtin_amdgcn_readlane(myrec.y, e + 2));
            float vb1 = __uint_as_float(__builtin_amdgcn_readlane(myrec.y, e + 3));
            unsigned s0 = half ? sb0 : sa0;  float v0 = half ? vb0 : va0;
            unsigned s1 = half ? sb1 : sa1;  float v1 = half ? vb1 : va1;
            a0 += v0 * __half2float(dense[(size_t)s0 * NOUT + l32]);
            a1 += v1 * __half2float(dense[(size_t)s1 * NOUT + l32]);
        }
        for (; e < rem; e += 2) {
            unsigned sa = __builtin_amdgcn_readlane(myrec.x, e);
            float va = __uint_as_float(__builtin_amdgcn_readlane(myrec.y, e));
            if (e + 1 < rem) {
                unsigned sb = __builtin_amdgcn_readlane(myrec.x, e + 1);
                float vb = __uint_as_float(__builtin_amdgcn_readlane(myrec.y, e + 1));
                unsigned s = half ? sb : sa;  float v = half ? vb : va;
                a0 += v * __half2float(dense[(size_t)s * NOUT + l32]);
            } else if (half == 0) {
                a0 += va * __half2float(dense[(size_t)sa * NOUT + l32]);
            }
        }
    }
    float acc = a0 + a1;
    acc += __shfl_xor(acc, 32, 64);
    if (half == 0) out[(size_t)d * NOUT + l32] = acc + b2[l32];
}

// ---------------------------------------------------------------
// GEMM2: s2[N,32] (fp16) = h[N,64] (fp16) @ W2[64,32]
// Same register-blocked template as gemm1: 4 nodes x 4 cols / thread.
// ---------------------------------------------------------------
__global__ __launch_bounds__(256) void gemm2_kernel(const __half* __restrict__ h,
                                                    const float* __restrict__ W2,
                                                    __half* __restrict__ s2) {
    __shared__ float wlds[NHID * NOUT];        // 8 KB, [k][col]
    const int tid = threadIdx.x;
    for (int i = tid; i < NHID * NOUT; i += 256) wlds[i] = W2[i];

    const int cg = (tid & 7) * 4;              // col group: 4 of 32
    const int ng = tid >> 3;                   // node group 0..31
    const int n0 = blockIdx.x * 128 + ng * 4;  // 4 nodes per thread

    int nidx[4];
#pragma unroll
    for (int i = 0; i < 4; ++i) {
        int n = n0 + i;
        nidx[i] = (n < N_NODES) ? n : (N_NODES - 1);
    }
    __syncthreads();

    float acc[4][4];
#pragma unroll
    for (int i = 0; i < 4; ++i)
#pragma unroll
        for (int j = 0; j < 4; ++j) acc[i][j] = 0.f;

    for (int k0 = 0; k0 < NHID; k0 += 8) {
        float hx[4][8];
#pragma unroll
        for (int i = 0; i < 4; ++i) {
            union { float4 f4; __half2 h2[4]; } u;
            u.f4 = *(const float4*)&h[(size_t)nidx[i] * NHID + k0];
#pragma unroll
            for (int j = 0; j < 4; ++j) {
                float2 f = __half22float2(u.h2[j]);
                hx[i][j * 2]     = f.x;
                hx[i][j * 2 + 1] = f.y;
            }
        }
#pragma unroll
        for (int kk = 0; kk < 8; ++kk) {
            float4 w = *(const float4*)&wlds[(k0 + kk) * NOUT + cg];
#pragma unroll
            for (int i = 0; i < 4; ++i) {
                float xv = hx[i][kk];
                acc[i][0] += w.x * xv; acc[i][1] += w.y * xv;
                acc[i][2] += w.z * xv; acc[i][3] += w.w * xv;
            }
        }
    }
#pragma unroll
    for (int i = 0; i < 4; ++i) {
        int n = n0 + i;
        if (n < N_NODES) {
            union { __half2 h2[2]; uint2 u; } pk;
            pk.h2[0] = __floats2half2_rn(acc[i][0], acc[i][1]);
            pk.h2[1] = __floats2half2_rn(acc[i][2], acc[i][3]);
            *(uint2*)&s2[(size_t)n * NOUT + cg] = pk.u;
        }
    }
}

extern "C" void kernel_launch(void* const* d_in, const int* in_sizes, int n_in,
                              void* d_out, int out_size, void* d_ws, size_t ws_size,
                              hipStream_t stream) {
    const float* x        = (const float*)d_in[0];
    const float* adj_vals = (const float*)d_in[1];
    const float* W1       = (const float*)d_in[2];
    const float* b1       = (const float*)d_in[3];
    const float* W2       = (const float*)d_in[4];
    const float* b2       = (const float*)d_in[5];
    const int*   esrc     = (const int*)d_in[6];
    const int*   edst     = (const int*)d_in[7];
    float*       out      = (float*)d_out;

    // ws layout (~38.8 MB used, all rewritten every call):
    //   support[6.4M half = 12.8MB]  (s2 aliases: support dead after spmm1)
    //   h[6.4M half = 12.8MB]        (coarse recs alias h: dead before h write)
    //   recs2[1.6M uint2 = 12.8MB] | offs[N+1] | counts | cbase | cursor
    char* W = (char*)d_ws;
    __half* support = (__half*)W;
    __half* h       = (__half*)(W + 12800000);
    uint2*  recsC   = (uint2*)h;
    uint2*  recs2   = (uint2*)(W + 25600000);
    int*    offs    = (int*)(W + 38400000);                // N+1
    int*    counts  = offs + (N_NODES + 2);
    int*    cbase   = counts + 512;                        // NB+1
    int*    cursor  = cbase + 512;                         // NB
    __half* s2      = support;

    // 1. support = x @ W1
    gemm1_kernel<<<(N_NODES + 63) / 64, 256, 0, stream>>>(x, W1, support);

    // 2. bucket CSR build (shared by both SpMMs)
    zero_counts_kernel<<<(NB + 255) / 256, 256, 0, stream>>>(counts);
    bucket_hist_kernel<<<NCHUNK, 256, 0, stream>>>(edst, counts);
    bucket_scan_kernel<<<1, 256, 0, stream>>>(counts, cbase, cursor);
    bucket_scatter_kernel<<<NCHUNK, 256, 0, stream>>>(adj_vals, esrc, edst, cursor, recsC);
    fine_sort_kernel<<<NB, 256, 0, stream>>>(cbase, recsC, recs2, offs);

    // 3. h = relu(A @ support + b1)   (overwrites recsC region — recsC dead)
    spmm1_csr_kernel<<<(N_NODES * 64 + 255) / 256, 256, 0, stream>>>(offs, recs2,
                                                                     support, b1, h);

    // 4. s2 = h @ W2  (into support region)
    gemm2_kernel<<<(N_NODES + 127) / 128, 256, 0, stream>>>(h, W2, s2);

    // 5. out = A @ s2 + b2
    spmm2_csr_kernel<<<(N_NODES * 64 + 255) / 256, 256, 0, stream>>>(offs, recs2,
                                                                     s2, b2, out);
}